// Round 1
// baseline (1723.644 us; speedup 1.0000x reference)
//
#include <hip/hip_runtime.h>
#include <cstdint>
#include <cstddef>

#define NPTS   262144
#define NNB    16
#define NKP    15
#define CIN    128
#define D2     64
#define COUT   256
#define PINF   0.04f
#define NSLOPE 0.2f
#define BEPS   1e-5f

// ---------------- workspace layout (float element offsets) ----------------
#define WS_BN1_SUM  0            // 64
#define WS_BN1_SQ   64           // 64
#define WS_KP_SUM   128          // 64
#define WS_KP_SQ    192          // 64
#define WS_U2_DSUM  256          // 256
#define WS_U2_DSQ   512          // 256
#define WS_PAIRCNT  768          // 1 int
#define WS_FLAGS    1024         // NPTS ints
#define WS_KPPRE    (1024 + NPTS)                      // NPTS*64 floats (zeroed)
#define WS_ZERO_END (WS_KPPRE + (size_t)NPTS * D2)     // end of zeroed zone
#define WS_HPRE     WS_ZERO_END                        // NPTS*64 floats
#define WS_DERIV    (WS_HPRE + (size_t)NPTS * D2)      // 2048 floats of derived params
#define D_S1   0
#define D_T1   64
#define D_SKP  128
#define D_TKP  192
#define D_ZB   256
#define D_S2   320
#define D_T2   576
#define D_BU2  832
#define D_FB   1088
#define WS_PAIRS    (WS_DERIV + 2048)                  // int2 per pair, cap NPTS*NNB

__device__ __forceinline__ float lrelu(float v) { return v >= 0.f ? v : NSLOPE * v; }

// ---------------- k0: zero the stats/flags/kp_pre zone ----------------
__global__ void k0_zero(float* __restrict__ ws) {
  size_t n4 = WS_ZERO_END / 4;
  float4 z = make_float4(0.f, 0.f, 0.f, 0.f);
  for (size_t i = (size_t)blockIdx.x * blockDim.x + threadIdx.x; i < n4;
       i += (size_t)gridDim.x * blockDim.x)
    ((float4*)ws)[i] = z;
}

// ---------------- k1: fused GEMM  [h_pre | sc] = x @ [W1 | Wsc] ----------------
// grid (NPTS/64), block 256.  Block tile 64 rows x 320 cols (5 chunks of 64).
__global__ __launch_bounds__(256) void k1_gemm(const float* __restrict__ x,
                                               const float* __restrict__ W1,
                                               const float* __restrict__ Wsc,
                                               float* __restrict__ hpre,
                                               float* __restrict__ outp) {
  __shared__ __align__(16) float As[32][72];      // [k][m], stride 72 keeps 16B align
  __shared__ __align__(16) float Bs[5][32][64];   // [jchunk][k][n]
  const int t = threadIdx.x;
  const int row0 = blockIdx.x * 64;
  const int tx = t & 15, ty = t >> 4;
  float acc[5][4][4];
#pragma unroll
  for (int j5 = 0; j5 < 5; j5++)
#pragma unroll
    for (int i = 0; i < 4; i++)
#pragma unroll
      for (int j = 0; j < 4; j++) acc[j5][i][j] = 0.f;

  for (int k0 = 0; k0 < CIN; k0 += 32) {
    __syncthreads();
    {  // A tile: 64 rows x 32 k
      int r = t >> 2;
      int c = (t & 3) * 8;
      const float* src = &x[(size_t)(row0 + r) * CIN + k0 + c];
      float4 a0 = *(const float4*)src;
      float4 a1 = *(const float4*)(src + 4);
      As[c + 0][r] = a0.x; As[c + 1][r] = a0.y; As[c + 2][r] = a0.z; As[c + 3][r] = a0.w;
      As[c + 4][r] = a1.x; As[c + 5][r] = a1.y; As[c + 6][r] = a1.z; As[c + 7][r] = a1.w;
    }
    {  // B tiles: 32 k x 64 cols, for all 5 column chunks
      int kk = t >> 3;
      int c = (t & 7) * 8;
#pragma unroll
      for (int j5 = 0; j5 < 5; j5++) {
        const float* B = (j5 == 0) ? &W1[(size_t)(k0 + kk) * D2 + c]
                                   : &Wsc[(size_t)(k0 + kk) * COUT + (j5 - 1) * 64 + c];
        float4 b0 = *(const float4*)B;
        float4 b1 = *(const float4*)(B + 4);
        *(float4*)&Bs[j5][kk][c] = b0;
        *(float4*)&Bs[j5][kk][c + 4] = b1;
      }
    }
    __syncthreads();
#pragma unroll
    for (int k = 0; k < 32; ++k) {
      float4 av = *(const float4*)&As[k][ty * 4];
      float a[4] = {av.x, av.y, av.z, av.w};
#pragma unroll
      for (int j5 = 0; j5 < 5; j5++) {
        float4 bv = *(const float4*)&Bs[j5][k][tx * 4];
        float b[4] = {bv.x, bv.y, bv.z, bv.w};
#pragma unroll
        for (int i = 0; i < 4; i++)
#pragma unroll
          for (int j = 0; j < 4; j++) acc[j5][i][j] = fmaf(a[i], b[j], acc[j5][i][j]);
      }
    }
  }
#pragma unroll
  for (int i = 0; i < 4; i++) {
    int r = row0 + ty * 4 + i;
    *(float4*)&hpre[(size_t)r * D2 + tx * 4] =
        make_float4(acc[0][i][0], acc[0][i][1], acc[0][i][2], acc[0][i][3]);
#pragma unroll
    for (int j5 = 1; j5 < 5; j5++)
      *(float4*)&outp[(size_t)r * COUT + (j5 - 1) * 64 + tx * 4] =
          make_float4(acc[j5][i][0], acc[j5][i][1], acc[j5][i][2], acc[j5][i][3]);
  }
}

// ---------------- k2: per-column sum / sumsq of h_pre ----------------
__global__ __launch_bounds__(256) void k2_stats(const float* __restrict__ hpre,
                                                float* __restrict__ ws) {
  const int t = threadIdx.x;
  const int col = t & 63;
  float s = 0.f, q = 0.f;
#pragma unroll 4
  for (int row = blockIdx.x * 4 + (t >> 6); row < NPTS; row += gridDim.x * 4) {
    float v = hpre[(size_t)row * D2 + col];
    s += v;
    q = fmaf(v, v, q);
  }
  __shared__ float red[256];
  red[t] = s;
  __syncthreads();
  if (t < 64) s = red[t] + red[t + 64] + red[t + 128] + red[t + 192];
  __syncthreads();
  red[t] = q;
  __syncthreads();
  if (t < 64) {
    q = red[t] + red[t + 64] + red[t + 128] + red[t + 192];
    atomicAdd(&ws[WS_BN1_SUM + col], s);
    atomicAdd(&ws[WS_BN1_SQ + col], q);
  }
}

// ---------------- k2b: finalize BN1 scale/shift ----------------
__global__ void k2b_fin1(const float* __restrict__ g1, const float* __restrict__ b1,
                         float* __restrict__ ws) {
  int c = threadIdx.x;  // 64
  float m = ws[WS_BN1_SUM + c] * (1.f / NPTS);
  float v = ws[WS_BN1_SQ + c] * (1.f / NPTS) - m * m;
  float sc = g1[c] / sqrtf(v + BEPS);
  ws[WS_DERIV + D_S1 + c] = sc;
  ws[WS_DERIV + D_T1 + c] = b1[c] - m * sc;
}

// ---------------- k3a: filter active (point, neighbor) pairs ----------------
__global__ __launch_bounds__(256) void k3a_filter(const int* __restrict__ idx,
                                                  const float* __restrict__ pos,
                                                  const float* __restrict__ kpts,
                                                  float* __restrict__ ws, int cap) {
  __shared__ float kp[NKP * 3];
  int t = threadIdx.x;
  if (t < NKP * 3) kp[t] = kpts[t];
  __syncthreads();
  int id = blockIdx.x * 256 + t;  // pair id < NPTS*NNB
  int p = id >> 4;
  int ia = idx[id];
  if (ia >= NPTS) return;  // shadow neighbor -> exact zero contribution
  float px = pos[p * 3 + 0], py = pos[p * 3 + 1], pz = pos[p * 3 + 2];
  float dx = pos[ia * 3 + 0] - px, dy = pos[ia * 3 + 1] - py, dz = pos[ia * 3 + 2] - pz;
  const float thr = PINF * PINF * 1.0002f;  // slightly inflated; w<=0 pairs add exact 0 later
  bool act = false;
#pragma unroll
  for (int k = 0; k < NKP; k++) {
    float ex = dx - kp[k * 3 + 0], ey = dy - kp[k * 3 + 1], ez = dz - kp[k * 3 + 2];
    float s = fmaf(ex, ex, fmaf(ey, ey, ez * ez));
    act = act || (s < thr);
  }
  if (act) {
    int slot = atomicAdd((int*)&ws[WS_PAIRCNT], 1);
    if (slot < cap) {
      int* pairs = (int*)&ws[WS_PAIRS];
      pairs[2 * slot] = p;
      pairs[2 * slot + 1] = ia;
    }
    ((int*)&ws[WS_FLAGS])[p] = 1;
  }
}

// ---------------- k3b: process active pairs (one wave per pair) ----------------
__global__ __launch_bounds__(64) void k3b_active(const float* __restrict__ pos,
                                                 const float* __restrict__ kpts,
                                                 const float* __restrict__ kpw,
                                                 float* __restrict__ ws, int cap) {
  __shared__ float kp[NKP * 3];
  __shared__ float fbuf[64];
  int t = threadIdx.x;
  if (t < NKP * 3) kp[t] = kpts[t];
  const int* pairs = (const int*)&ws[WS_PAIRS];
  int npairs = ((const int*)ws)[WS_PAIRCNT];
  if (npairs > cap) npairs = cap;
  const float* hpre = &ws[WS_HPRE];
  const float* s1 = &ws[WS_DERIV + D_S1];
  const float* t1 = &ws[WS_DERIV + D_T1];
  float* kppre = &ws[WS_KPPRE];
  __syncthreads();
  for (int i = blockIdx.x; i < npairs; i += gridDim.x) {
    int p = pairs[2 * i], ia = pairs[2 * i + 1];
    float px = pos[p * 3 + 0], py = pos[p * 3 + 1], pz = pos[p * 3 + 2];
    float dx = pos[ia * 3 + 0] - px, dy = pos[ia * 3 + 1] - py, dz = pos[ia * 3 + 2] - pz;
    float w[NKP];
#pragma unroll
    for (int k = 0; k < NKP; k++) {
      float ex = dx - kp[k * 3 + 0], ey = dy - kp[k * 3 + 1], ez = dz - kp[k * 3 + 2];
      float s = fmaf(ex, ex, fmaf(ey, ey, ez * ez));
      w[k] = fmaxf(0.f, 1.f - sqrtf(s) / PINF);  // exact 0 outside influence
    }
    float hv = hpre[(size_t)ia * D2 + t];
    float f = lrelu(fmaf(s1[t], hv, t1[t]));  // BN1 + LeakyReLU on the fly
    __syncthreads();
    fbuf[t] = f;
    __syncthreads();
    float accd = 0.f;
#pragma unroll
    for (int k = 0; k < NKP; k++) {
      if (w[k] > 0.f) {
        float mv = 0.f;
        const float* kw = &kpw[(size_t)k * D2 * D2 + t];
        for (int c = 0; c < D2; c++) mv = fmaf(fbuf[c], kw[(size_t)c * D2], mv);
        accd = fmaf(w[k], mv, accd);
      }
    }
    atomicAdd(&kppre[(size_t)p * D2 + t], accd);
  }
}

// ---------------- k4: BN_kp stats (active rows only; zeros contribute 0) ------
__global__ __launch_bounds__(256) void k4_stats_kp(float* __restrict__ ws) {
  const int t = threadIdx.x;
  const int* flags = (const int*)&ws[WS_FLAGS];
  const float* kppre = &ws[WS_KPPRE];
  __shared__ int q[256];
  __shared__ int qn;
  float s = 0.f, sq = 0.f;
  for (int base = blockIdx.x * 256; base < NPTS; base += gridDim.x * 256) {
    if (t == 0) qn = 0;
    __syncthreads();
    if (flags[base + t]) {
      int slot = atomicAdd(&qn, 1);
      q[slot] = base + t;
    }
    __syncthreads();
    int n = qn;
    for (int qi = t >> 6; qi < n; qi += 4) {
      float v = kppre[(size_t)q[qi] * D2 + (t & 63)];
      s += v;
      sq = fmaf(v, v, sq);
    }
    __syncthreads();
  }
  __shared__ float red[256];
  red[t] = s;
  __syncthreads();
  if (t < 64) s = red[t] + red[t + 64] + red[t + 128] + red[t + 192];
  __syncthreads();
  red[t] = sq;
  __syncthreads();
  if (t < 64) {
    sq = red[t] + red[t + 64] + red[t + 128] + red[t + 192];
    atomicAdd(&ws[WS_KP_SUM + t], s);
    atomicAdd(&ws[WS_KP_SQ + t], sq);
  }
}

// ---------------- k4b: finalize BN_kp; base z row; base u2 row ----------------
__global__ void k4b_fin_kp(const float* __restrict__ gkp, const float* __restrict__ bkp,
                           const float* __restrict__ W2, float* __restrict__ ws) {
  int t = threadIdx.x;  // 256
  __shared__ float zb[64];
  if (t < 64) {
    float m = ws[WS_KP_SUM + t] * (1.f / NPTS);
    float v = ws[WS_KP_SQ + t] * (1.f / NPTS) - m * m;
    float sc = gkp[t] / sqrtf(v + BEPS);
    float sh = bkp[t] - m * sc;
    ws[WS_DERIV + D_SKP + t] = sc;
    ws[WS_DERIV + D_TKP + t] = sh;
    float z = lrelu(sh);  // bn_kp(0) = shift
    ws[WS_DERIV + D_ZB + t] = z;
    zb[t] = z;
  }
  __syncthreads();
  float u = 0.f;
  for (int c = 0; c < 64; c++) u = fmaf(zb[c], W2[(size_t)c * COUT + t], u);
  ws[WS_DERIV + D_BU2 + t] = u;  // shared u2 row of all inactive points
}

// ---------------- k5: BN2 stats centered on base row (actives only) -----------
__global__ __launch_bounds__(256) void k5_stats_u2(const float* __restrict__ W2,
                                                   float* __restrict__ ws) {
  const int t = threadIdx.x;
  const int* flags = (const int*)&ws[WS_FLAGS];
  const float* kppre = &ws[WS_KPPRE];
  const float* skp = &ws[WS_DERIV + D_SKP];
  const float* tkp = &ws[WS_DERIV + D_TKP];
  float bu = ws[WS_DERIV + D_BU2 + t];
  __shared__ int q[256];
  __shared__ int qn;
  __shared__ float z[64];
  float ds = 0.f, dq = 0.f;
  for (int base = blockIdx.x * 256; base < NPTS; base += gridDim.x * 256) {
    if (t == 0) qn = 0;
    __syncthreads();
    if (flags[base + t]) {
      int slot = atomicAdd(&qn, 1);
      q[slot] = base + t;
    }
    __syncthreads();
    int n = qn;
    for (int qi = 0; qi < n; qi++) {
      int p = q[qi];
      if (t < 64) z[t] = lrelu(fmaf(skp[t], kppre[(size_t)p * D2 + t], tkp[t]));
      __syncthreads();
      float u = 0.f;
      for (int c = 0; c < 64; c++) u = fmaf(z[c], W2[(size_t)c * COUT + t], u);
      float du = u - bu;  // inactive rows have du == 0 exactly
      ds += du;
      dq = fmaf(du, du, dq);
      __syncthreads();
    }
  }
  atomicAdd(&ws[WS_U2_DSUM + t], ds);
  atomicAdd(&ws[WS_U2_DSQ + t], dq);
}

// ---------------- k6: finalize BN2; final base output row ----------------
__global__ void k6_fin2(const float* __restrict__ g2, const float* __restrict__ b2,
                        float* __restrict__ ws) {
  int t = threadIdx.x;  // 256
  float bu = ws[WS_DERIV + D_BU2 + t];
  float dm = ws[WS_U2_DSUM + t] * (1.f / NPTS);
  float dv = ws[WS_U2_DSQ + t] * (1.f / NPTS) - dm * dm;  // Var(u) = Var(u - base)
  float mean = bu + dm;
  float sc = g2[t] / sqrtf(dv + BEPS);
  float sh = b2[t] - mean * sc;
  ws[WS_DERIV + D_S2 + t] = sc;
  ws[WS_DERIV + D_T2 + t] = sh;
  ws[WS_DERIV + D_FB + t] = lrelu(fmaf(sc, bu, sh));
}

// ---------------- k7: final  out = lrelu(bn2(u2)) + sc  (sc already in d_out) --
__global__ __launch_bounds__(256) void k7_final(const float* __restrict__ W2,
                                                float* __restrict__ out,
                                                float* __restrict__ ws) {
  const int t = threadIdx.x;
  const int* flags = (const int*)&ws[WS_FLAGS];
  const float* kppre = &ws[WS_KPPRE];
  const float* skp = &ws[WS_DERIV + D_SKP];
  const float* tkp = &ws[WS_DERIV + D_TKP];
  const float* s2 = &ws[WS_DERIV + D_S2];
  const float* t2 = &ws[WS_DERIV + D_T2];
  const float* fb = &ws[WS_DERIV + D_FB];
  __shared__ int q[256];
  __shared__ int qn;
  __shared__ float z[64];
  const int sub = t >> 6;        // row subgroup 0..3
  const int jc = (t & 63) * 4;   // 4 cols per thread
  float4 fb4 = *(const float4*)&fb[jc];
  for (int base = blockIdx.x * 256; base < NPTS; base += gridDim.x * 256) {
    if (t == 0) qn = 0;
    __syncthreads();
    if (flags[base + t]) {
      int slot = atomicAdd(&qn, 1);
      q[slot] = base + t;
    }
    __syncthreads();
    // inactive rows: out = final_base + sc (4 rows per iteration, float4)
    for (int r0 = 0; r0 < 256; r0 += 4) {
      int p = base + r0 + sub;
      if (!flags[p]) {
        float4 s4 = *(const float4*)&out[(size_t)p * COUT + jc];
        s4.x += fb4.x; s4.y += fb4.y; s4.z += fb4.z; s4.w += fb4.w;
        *(float4*)&out[(size_t)p * COUT + jc] = s4;
      }
    }
    int n = qn;
    for (int qi = 0; qi < n; qi++) {
      int p = q[qi];
      if (t < 64) z[t] = lrelu(fmaf(skp[t], kppre[(size_t)p * D2 + t], tkp[t]));
      __syncthreads();
      float u = 0.f;
      for (int c = 0; c < 64; c++) u = fmaf(z[c], W2[(size_t)c * COUT + t], u);
      float val = lrelu(fmaf(s2[t], u, t2[t]));
      out[(size_t)p * COUT + t] += val;  // sc row untouched by inactive pass
      __syncthreads();
    }
  }
}

// ---------------- launch ----------------
extern "C" void kernel_launch(void* const* d_in, const int* in_sizes, int n_in,
                              void* d_out, int out_size, void* d_ws, size_t ws_size,
                              hipStream_t stream) {
  const float* x    = (const float*)d_in[0];
  const float* pos  = (const float*)d_in[1];
  const int*   idx  = (const int*)d_in[2];
  const float* W1   = (const float*)d_in[3];
  const float* g1   = (const float*)d_in[4];
  const float* b1   = (const float*)d_in[5];
  const float* kpts = (const float*)d_in[6];
  const float* kpw  = (const float*)d_in[7];
  const float* gkp  = (const float*)d_in[8];
  const float* bkp  = (const float*)d_in[9];
  const float* W2   = (const float*)d_in[10];
  const float* g2   = (const float*)d_in[11];
  const float* b2   = (const float*)d_in[12];
  const float* Wsc  = (const float*)d_in[13];
  float* out = (float*)d_out;
  float* ws = (float*)d_ws;

  long long cap_ll = ((long long)(ws_size / 4) - (long long)WS_PAIRS) / 2;
  if (cap_ll < 0) cap_ll = 0;
  if (cap_ll > (long long)NPTS * NNB) cap_ll = (long long)NPTS * NNB;
  int cap = (int)cap_ll;

  k0_zero<<<2048, 256, 0, stream>>>(ws);
  k1_gemm<<<NPTS / 64, 256, 0, stream>>>(x, W1, Wsc, &ws[WS_HPRE], out);
  k2_stats<<<1024, 256, 0, stream>>>(&ws[WS_HPRE], ws);
  k2b_fin1<<<1, 64, 0, stream>>>(g1, b1, ws);
  k3a_filter<<<NPTS * NNB / 256, 256, 0, stream>>>(idx, pos, kpts, ws, cap);
  k3b_active<<<4096, 64, 0, stream>>>(pos, kpts, kpw, ws, cap);
  k4_stats_kp<<<512, 256, 0, stream>>>(ws);
  k4b_fin_kp<<<1, 256, 0, stream>>>(gkp, bkp, W2, ws);
  k5_stats_u2<<<512, 256, 0, stream>>>(W2, ws);
  k6_fin2<<<1, 256, 0, stream>>>(g2, b2, ws);
  k7_final<<<512, 256, 0, stream>>>(W2, out, ws);
}